// Round 18
// baseline (397.645 us; speedup 1.0000x reference)
//
#include <hip/hip_runtime.h>

#define H   8
#define DK  64
#define DV  64
#define DM  512
#define B_  8
#define LQ  512
#define LK  1024
#define NEG (-1e30f)

// Q pre-scale: 0.125 * log2(e). QK^T then yields log2-domain scores.
#define QSCALE 0.18033688011112042f
// 16 * log2(e): exp(s*0.125 - 16) == exp2(s' - C16)
#define C16    23.083120654223414f

typedef __attribute__((ext_vector_type(8))) short bf16x8;
typedef __attribute__((ext_vector_type(4))) float f32x4;

__device__ __forceinline__ short f2bf(float f) {
    union { float f; unsigned u; } x; x.f = f;
    unsigned r = x.u + 0x7fffu + ((x.u >> 16) & 1u);
    return (short)(r >> 16);
}
__device__ __forceinline__ unsigned pack2(float a, float b) {
    return (unsigned)(unsigned short)f2bf(a) | ((unsigned)(unsigned short)f2bf(b) << 16);
}
__device__ __forceinline__ float bflo(unsigned w) {
    union { unsigned u; float f; } x; x.u = w << 16; return x.f;
}
__device__ __forceinline__ float bfhi(unsigned w) {
    union { unsigned u; float f; } x; x.u = w & 0xFFFF0000u; return x.f;
}
__device__ __forceinline__ unsigned pkh(float a, float b) {
    union { _Float16 h[2]; unsigned u; } x;
    x.h[0] = (_Float16)a; x.h[1] = (_Float16)b; return x.u;
}
__device__ __forceinline__ float uph(unsigned w, int i) {
    union { unsigned u; _Float16 h[2]; } x; x.u = w;
    return (float)x.h[i];
}
// LDS-only barrier: lets wave-private global ops (NT stores, preloads) stay
// in flight across the barrier instead of the vmcnt(0) drain __syncthreads emits.
__device__ __forceinline__ void bar_lds() {
    asm volatile("s_waitcnt lgkmcnt(0)" ::: "memory");
    __builtin_amdgcn_s_barrier();
}

// ---------------- kernel 1: prep (weight transpose + X bf16 precast) ---------
__global__ __launch_bounds__(256) void prep_kernel(
    const float* __restrict__ wqs, const float* __restrict__ wks,
    const float* __restrict__ wvs, const float* __restrict__ wfc,
    const float* __restrict__ q, const float* __restrict__ k,
    const float* __restrict__ v, short* __restrict__ WT,
    short* __restrict__ Qb, short* __restrict__ Kb, short* __restrict__ Vb) {
    __shared__ float tile[32][33];
    int bx = blockIdx.x;
    int t = threadIdx.x;
    if (bx < 1024) {
        int mat = bx >> 8, tt = bx & 255;
        int k0 = (tt >> 4) * 32, n0 = (tt & 15) * 32;
        int tx = t & 31, ty = t >> 5;   // 32 x 8
        const float* src = (mat == 0) ? wqs : (mat == 1) ? wks : (mat == 2) ? wvs : wfc;
        short* dst = WT + (size_t)mat * DM * DM;
#pragma unroll
        for (int i = 0; i < 4; i++)
            tile[ty + i * 8][tx] = src[(size_t)(k0 + ty + i * 8) * DM + n0 + tx];
        __syncthreads();
#pragma unroll
        for (int i = 0; i < 4; i++)
            dst[(size_t)(n0 + ty + i * 8) * DM + k0 + tx] = f2bf(tile[tx][ty + i * 8]);
    } else {
        int cb2 = bx - 1024;
        const float* src; short* dst; size_t base; float sc = 1.0f;
        if (cb2 < 1024)      { src = q; dst = Qb; base = (size_t)cb2 * 2048; sc = QSCALE; }
        else if (cb2 < 3072) { src = k; dst = Kb; base = (size_t)(cb2 - 1024) * 2048; }
        else                 { src = v; dst = Vb; base = (size_t)(cb2 - 3072) * 2048; }
        size_t idx = base + (size_t)t * 8;
        float4 x0 = *(const float4*)(src + idx);
        float4 x1 = *(const float4*)(src + idx + 4);
        union { short s[8]; uint4 u; } pk;
        pk.s[0] = f2bf(x0.x * sc); pk.s[1] = f2bf(x0.y * sc);
        pk.s[2] = f2bf(x0.z * sc); pk.s[3] = f2bf(x0.w * sc);
        pk.s[4] = f2bf(x1.x * sc); pk.s[5] = f2bf(x1.y * sc);
        pk.s[6] = f2bf(x1.z * sc); pk.s[7] = f2bf(x1.w * sc);
        *(uint4*)(dst + idx) = pk.u;
    }
}

// ---------------- kernel 2: projections + prior transpose + mask compress ---
__global__ __launch_bounds__(256) void proj_all(
    const short* __restrict__ Xq, const short* __restrict__ Xk,
    const short* __restrict__ Xv, const short* __restrict__ WT,
    const float* __restrict__ prior, const float* __restrict__ km,
    const float* __restrict__ mm,
    short* __restrict__ QHb, short* __restrict__ KHb, short* __restrict__ VT,
    short* __restrict__ prtb, unsigned short* __restrict__ kmbits,
    unsigned short* __restrict__ mmbits) {
    __shared__ float tile[64][65];
    int bx = blockIdx.x;
    int t = threadIdx.x;
    if (bx >= 1344) {
        if (blockIdx.y != 0) return;
        int rr = (bx - 1344) * 4 + (t >> 6);    // row in [0, B*LQ)
        int lane = t & 63;
        const float* kmr = km + (size_t)rr * LK;
        const float* mmr = mm + (size_t)rr * LK;
        unsigned kb = 0, mb = 0;
#pragma unroll
        for (int c = 0; c < 4; c++) {
            float4 k4 = *(const float4*)(kmr + c * 256 + lane * 4);
            float4 m4 = *(const float4*)(mmr + c * 256 + lane * 4);
            kb |= (unsigned)(k4.x != 0.f) << (c * 4 + 0);
            kb |= (unsigned)(k4.y != 0.f) << (c * 4 + 1);
            kb |= (unsigned)(k4.z != 0.f) << (c * 4 + 2);
            kb |= (unsigned)(k4.w != 0.f) << (c * 4 + 3);
            mb |= (unsigned)(m4.x != 0.f) << (c * 4 + 0);
            mb |= (unsigned)(m4.y != 0.f) << (c * 4 + 1);
            mb |= (unsigned)(m4.z != 0.f) << (c * 4 + 2);
            mb |= (unsigned)(m4.w != 0.f) << (c * 4 + 3);
        }
        kmbits[(size_t)rr * 64 + lane] = (unsigned short)kb;
        mmbits[(size_t)rr * 64 + lane] = (unsigned short)mb;
        return;
    }
    if (bx >= 320) {
        if (blockIdx.y != 0) return;
        int tt = bx - 320;
        int b = tt >> 7, rem = tt & 127;        // 128 tiles: 16 (k) x 8 (q)
        int k0 = (rem >> 3) * 64, q0 = (rem & 7) * 64;
        int tx = t & 63, ty = t >> 6;           // 64 x 4
        const float* src = prior + (size_t)b * LK * LQ;
        short* dst = prtb + (size_t)b * LQ * LK;
#pragma unroll
        for (int i = 0; i < 16; i++)
            tile[ty + i * 4][tx] = src[(size_t)(k0 + ty + i * 4) * LQ + q0 + tx];
        __syncthreads();
#pragma unroll
        for (int i = 0; i < 16; i++)
            dst[(size_t)(q0 + ty + i * 4) * LK + k0 + tx] = f2bf(tile[tx][ty + i * 4] + 1e-8f);
        return;
    }
    const short* X; const short* W; short* out; int mode, r0;
    if (bx < 64)       { X = Xq; W = WT;          out = QHb; mode = 0; r0 = bx * 64; }
    else if (bx < 192) { X = Xk; W = WT + 262144; out = KHb; mode = 0; r0 = (bx - 64) * 64; }
    else               { X = Xv; W = WT + 524288; out = VT;  mode = 1; r0 = (bx - 192) * 64; }
    int tid = threadIdx.x;
    int wid = tid >> 6, lane = tid & 63, g = lane >> 4, ln = lane & 15;
    int wr = wid >> 1, wc = wid & 1;
    int cb = blockIdx.y * 256;
    f32x4 acc[4][2][2] = {};
    for (int kb = 0; kb < 16; kb++) {
        bf16x8 a[2];
#pragma unroll
        for (int i = 0; i < 2; i++) {
            int row = r0 + wr * 32 + i * 16 + ln;
            a[i] = *(const bf16x8*)(X + (size_t)row * DM + kb * 32 + g * 8);
        }
#pragma unroll
        for (int cc = 0; cc < 4; cc++) {
            bf16x8 b[2];
#pragma unroll
            for (int j = 0; j < 2; j++) {
                int col = cb + cc * 64 + wc * 32 + j * 16 + ln;
                b[j] = *(const bf16x8*)(W + (size_t)col * DM + kb * 32 + g * 8);
            }
#pragma unroll
            for (int i = 0; i < 2; i++)
#pragma unroll
                for (int j = 0; j < 2; j++)
                    acc[cc][i][j] = __builtin_amdgcn_mfma_f32_16x16x32_bf16(a[i], b[j], acc[cc][i][j], 0, 0, 0);
        }
    }
#pragma unroll
    for (int cc = 0; cc < 4; cc++)
#pragma unroll
        for (int i = 0; i < 2; i++)
#pragma unroll
            for (int j = 0; j < 2; j++) {
                int colg = cb + cc * 64 + wc * 32 + j * 16 + ln;
                if (mode == 0) {
#pragma unroll
                    for (int r = 0; r < 4; r++) {
                        int rowg = r0 + wr * 32 + i * 16 + g * 4 + r;
                        out[(size_t)rowg * DM + colg] = f2bf(acc[cc][i][j][r]);
                    }
                } else {
                    int hh = colg >> 6, d = colg & 63;
                    int rbase = r0 + wr * 32 + i * 16 + g * 4;
                    int bb = rbase >> 10, kk = rbase & 1023;
                    union { short s[4]; unsigned long long u; } pk;
#pragma unroll
                    for (int r = 0; r < 4; r++) pk.s[r] = f2bf(acc[cc][i][j][r]);
                    *(unsigned long long*)(out + ((size_t)((hh * B_ + bb) * DV + d)) * LK + kk) = pk.u;
                }
            }
}

// ---------------- kernel 3: fused attention (r16 + 2-heads-per-block loop) --
// Loop h in {h0, h0+1}: C(h0)'s NT stores drain under A(h1)'s MFMA/K-loads
// (bar_lds keeps them in flight); mask/qm/prior preload amortized 2x.
#define SROWB 2064   // bytes per LDS row: 1032 halfs
__global__ __launch_bounds__(512, 6) void attn_kernel(
    const short* __restrict__ QHb, const short* __restrict__ KHb,
    const short* __restrict__ VT, const short* __restrict__ prtb,
    const unsigned short* __restrict__ kmbits, const unsigned short* __restrict__ mmbits,
    const float* __restrict__ qm, float* __restrict__ p_out,
    float* __restrict__ raw_out, float* __restrict__ lgp_out,
    short* __restrict__ outh) {
    __shared__ char lds[16 * SROWB];
    int tid = threadIdx.x;
    int wid = tid >> 6, lane = tid & 63, g = lane >> 4, ln = lane & 15;
    int q0 = blockIdx.x * 16, b = blockIdx.y, h0 = blockIdx.z * 2;
    int kw0 = wid * 128;
    int row0 = wid * 2;
    const size_t rb0 = (size_t)(b * LQ + q0 + row0);

    // ---- preload bitmasks + qm + prior ONCE (h-independent) ----
    unsigned kmb[2], mmb[2];
    float qmv[2];
    uint2 prW[2][4];
#pragma unroll
    for (int rr = 0; rr < 2; rr++) {
        kmb[rr] = kmbits[(rb0 + rr) * 64 + lane];
        mmb[rr] = mmbits[(rb0 + rr) * 64 + lane];
        qmv[rr] = qm[rb0 + rr];
#pragma unroll
        for (int c = 0; c < 4; c++)
            prW[rr][c] = *(const uint2*)(prtb + (rb0 + rr) * LK + c * 256 + lane * 4);
    }

#pragma unroll 1
    for (int hi = 0; hi < 2; hi++) {
        int h = h0 + hi;
        if (hi) bar_lds();   // protect ptile reads (prev D) from new score writes

        // ---- pass A: log2-domain scores into LDS (f16) ----
        {
            const short* qp = QHb + ((size_t)(b * LQ + q0 + ln)) * DM + h * DK + g * 8;
            bf16x8 bq0 = *(const bf16x8*)qp;
            bf16x8 bq1 = *(const bf16x8*)(qp + 32);
#pragma unroll
            for (int kt = 0; kt < 8; kt++) {
                int k0 = kw0 + kt * 16;
                const short* kp = KHb + ((size_t)(b * LK + k0 + ln)) * DM + h * DK + g * 8;
                bf16x8 ak0 = *(const bf16x8*)kp;
                bf16x8 ak1 = *(const bf16x8*)(kp + 32);
                f32x4 sa = {0.f, 0.f, 0.f, 0.f};
                sa = __builtin_amdgcn_mfma_f32_16x16x32_bf16(ak0, bq0, sa, 0, 0, 0);
                sa = __builtin_amdgcn_mfma_f32_16x16x32_bf16(ak1, bq1, sa, 0, 0, 0);
                uint2 sp;
                sp.x = pkh(sa[0], sa[1]);
                sp.y = pkh(sa[2], sa[3]);
                *(uint2*)(lds + ln * SROWB + (k0 + g * 4) * 2) = sp;
            }
        }
        bar_lds();

        // ---- pass B: per-wave rows; reg prior; exp2; bf16 carry ----
        float s1[2] = {0.f, 0.f}, s2[2] = {0.f, 0.f};
        uint2 xc[2][4];
#pragma unroll
        for (int rr = 0; rr < 2; rr++) {
            const char* svp = lds + (row0 + rr) * SROWB;
#pragma unroll
            for (int c = 0; c < 4; c++) {
                int e0 = c * 256 + lane * 4;
                uint2 prv = prW[rr][c];
                uint2 sp = *(const uint2*)(svp + e0 * 2);
                float sv[4] = { uph(sp.x, 0), uph(sp.x, 1), uph(sp.y, 0), uph(sp.y, 1) };
                float pr[4] = { bflo(prv.x), bfhi(prv.x), bflo(prv.y), bfhi(prv.y) };
                float xr[4];
#pragma unroll
                for (int r = 0; r < 4; r++) {
                    float kmf = (float)((kmb[rr] >> (c * 4 + r)) & 1u);
                    float e = kmf * __builtin_amdgcn_exp2f(sv[r] - C16);
                    float x = e * pr[r];
                    s1[rr] += e;
                    s2[rr] += x;
                    xr[r] = x;
                }
                xc[rr][c].x = pack2(xr[0], xr[1]);
                xc[rr][c].y = pack2(xr[2], xr[3]);
            }
        }
#pragma unroll
        for (int m = 1; m < 64; m <<= 1) {
            s1[0] += __shfl_xor(s1[0], m, 64);
            s1[1] += __shfl_xor(s1[1], m, 64);
            s2[0] += __shfl_xor(s2[0], m, 64);
            s2[1] += __shfl_xor(s2[1], m, 64);
        }

        // ---- pass C: contiguous non-temporal stores + LDS p-tile ----
#pragma unroll
        for (int rr = 0; rr < 2; rr++) {
            float inv1 = 1.0f / s1[rr];
            float inv2 = 1.0f / s2[rr];
            const size_t ob = ((size_t)((h * B_ + b) * LQ + q0 + row0 + rr)) * LK;
            short* pfp = (short*)(lds + (row0 + rr) * SROWB);
#pragma unroll
            for (int c = 0; c < 4; c++) {
                int e0 = c * 256 + lane * 4;
                float xv[4] = { bflo(xc[rr][c].x), bfhi(xc[rr][c].x),
                                bflo(xc[rr][c].y), bfhi(xc[rr][c].y) };
                f32x4 pw, rw, lw;
                union { short s[4]; unsigned long long u; } pk;
#pragma unroll
                for (int r = 0; r < 4; r++) {
                    float mmf = (float)((mmb[rr] >> (c * 4 + r)) & 1u);
                    float xr = xv[r];
                    float p0 = xr * inv2;
                    float praw = p0 * qmv[rr];
                    float pfin = praw * mmf;
                    float lgp = fmaxf(__logf(xr * inv1), -1e30f);
                    pw[r] = pfin;
                    rw[r] = praw;
                    lw[r] = lgp;
                    pk.s[r] = f2bf(pfin);
                }
                __builtin_nontemporal_store(pw, (f32x4*)(p_out + ob + e0));
                __builtin_nontemporal_store(rw, (f32x4*)(raw_out + ob + e0));
                __builtin_nontemporal_store(lw, (f32x4*)(lgp_out + ob + e0));
                *(unsigned long long*)(pfp + e0) = pk.u;
            }
        }
        bar_lds();

        // ---- pass D: PV on waves 0-3 (stores of this h drain under next A) --
        if (wid < 4) {
            f32x4 oacc = {0.f, 0.f, 0.f, 0.f};
            int d0 = wid * 16;
            const short* vrow = VT + ((size_t)((h * B_ + b) * DV + d0 + ln)) * LK;
            const short* prow = (const short*)(lds + ln * SROWB);
            for (int kc = 0; kc < 32; kc++) {
                bf16x8 ap = *(const bf16x8*)(prow + kc * 32 + g * 8);
                bf16x8 bv = *(const bf16x8*)(vrow + kc * 32 + g * 8);
                oacc = __builtin_amdgcn_mfma_f32_16x16x32_bf16(ap, bv, oacc, 0, 0, 0);
            }
#pragma unroll
            for (int r = 0; r < 4; r++) {
                int row = q0 + g * 4 + r;
                outh[((size_t)(b * LQ + row)) * DM + h * DV + d0 + ln] = f2bf(oacc[r]);
            }
        }
    }
}

// ---------------- kernel 4: out = outh @ w_fc + residual --------------------
__global__ __launch_bounds__(256) void final_kernel(
    const short* __restrict__ outh, const short* __restrict__ WTfc,
    const float* __restrict__ qres, float* __restrict__ out) {
    int tid = threadIdx.x;
    int wid = tid >> 6, lane = tid & 63, g = lane >> 4, ln = lane & 15;
    int wr = wid >> 1, wc = wid & 1;
    int r0 = blockIdx.x * 64, c0 = blockIdx.y * 64;
    f32x4 acc[2][2] = {};
    for (int kb = 0; kb < 16; kb++) {
        bf16x8 a[2], b[2];
#pragma unroll
        for (int i = 0; i < 2; i++)
            a[i] = *(const bf16x8*)(outh + ((size_t)(r0 + wr * 32 + i * 16 + ln)) * DM + kb * 32 + g * 8);
#pragma unroll
        for (int j = 0; j < 2; j++)
            b[j] = *(const bf16x8*)(WTfc + ((size_t)(c0 + wc * 32 + j * 16 + ln)) * DM + kb * 32 + g * 8);
#pragma unroll
        for (int i = 0; i < 2; i++)
#pragma unroll
            for (int j = 0; j < 2; j++)
                acc[i][j] = __builtin_amdgcn_mfma_f32_16x16x32_bf16(a[i], b[j], acc[i][j], 0, 0, 0);
    }
#pragma unroll
    for (int i = 0; i < 2; i++)
#pragma unroll
        for (int j = 0; j < 2; j++)
#pragma unroll
            for (int r = 0; r < 4; r++) {
                int row = r0 + wr * 32 + i * 16 + g * 4 + r;
                int col = c0 + wc * 32 + j * 16 + ln;
                float v = acc[i][j][r] + qres[(size_t)row * DM + col];
                __builtin_nontemporal_store(v, out + (size_t)row * DM + col);
            }
}

extern "C" void kernel_launch(void* const* d_in, const int* in_sizes, int n_in,
                              void* d_out, int out_size, void* d_ws, size_t ws_size,
                              hipStream_t stream) {
    (void)in_sizes; (void)n_in; (void)out_size; (void)ws_size;
    const float* q     = (const float*)d_in[0];
    const float* k     = (const float*)d_in[1];
    const float* v     = (const float*)d_in[2];
    const float* wqs   = (const float*)d_in[3];
    const float* wks   = (const float*)d_in[4];
    const float* wvs   = (const float*)d_in[5];
    const float* wfc   = (const float*)d_in[6];
    const float* km    = (const float*)d_in[7];
    const float* qm    = (const float*)d_in[8];
    const float* mm    = (const float*)d_in[9];
    const float* prior = (const float*)d_in[10];

    char* ws = (char*)d_ws;
    short* WT               = (short*)(ws);                     // 2 MiB
    short* QHb              = (short*)(ws + 2097152);           // 4 MiB
    short* KHb              = (short*)(ws + 6291456);           // 8 MiB
    short* VT               = (short*)(ws + 14680064);          // 8 MiB
    short* prtb             = (short*)(ws + 23068672);          // 8 MiB (bf16)
    short* outh             = (short*)(ws + 31457280);          // 4 MiB
    unsigned short* kmbits  = (unsigned short*)(ws + 35651584); // 512 KiB
    unsigned short* mmbits  = (unsigned short*)(ws + 36175872); // 512 KiB
    short* Qb               = (short*)(ws + 36700160);          // 4 MiB (bf16, prescaled)
    short* Kb               = (short*)(ws + 40894464);          // 8 MiB
    short* Vb               = (short*)(ws + 49283072);          // 8 MiB -> ends 55 MiB

    float* out     = (float*)d_out;
    float* p_out   = out + 2097152;
    float* raw_out = p_out + 33554432;
    float* lgp_out = raw_out + 33554432;

    prep_kernel<<<dim3(6144), dim3(256), 0, stream>>>(wqs, wks, wvs, wfc, q, k, v,
                                                      WT, Qb, Kb, Vb);
    proj_all<<<dim3(2368, 2), 256, 0, stream>>>(Qb, Kb, Vb, WT, prior, km, mm,
                                                QHb, KHb, VT, prtb, kmbits, mmbits);
    attn_kernel<<<dim3(32, 8, 4), dim3(512), 0, stream>>>(QHb, KHb, VT, prtb, kmbits, mmbits,
                                                          qm, p_out, raw_out, lgp_out, outh);
    final_kernel<<<dim3(64, 8), 256, 0, stream>>>(outh, WT + 786432, q, out);
}

// Round 19
// 193.043 us; speedup vs baseline: 2.0599x; 2.0599x over previous
//
#include <hip/hip_runtime.h>

#define H   8
#define DK  64
#define DV  64
#define DM  512
#define B_  8
#define LQ  512
#define LK  1024
#define NEG (-1e30f)

// Q pre-scale: 0.125 * log2(e). QK^T then yields log2-domain scores.
#define QSCALE 0.18033688011112042f
// 16 * log2(e): exp(s*0.125 - 16) == exp2(s' - C16)
#define C16    23.083120654223414f

typedef __attribute__((ext_vector_type(8))) short bf16x8;
typedef __attribute__((ext_vector_type(4))) float f32x4;

__device__ __forceinline__ short f2bf(float f) {
    union { float f; unsigned u; } x; x.f = f;
    unsigned r = x.u + 0x7fffu + ((x.u >> 16) & 1u);
    return (short)(r >> 16);
}
__device__ __forceinline__ unsigned pack2(float a, float b) {
    return (unsigned)(unsigned short)f2bf(a) | ((unsigned)(unsigned short)f2bf(b) << 16);
}
__device__ __forceinline__ float bflo(unsigned w) {
    union { unsigned u; float f; } x; x.u = w << 16; return x.f;
}
__device__ __forceinline__ float bfhi(unsigned w) {
    union { unsigned u; float f; } x; x.u = w & 0xFFFF0000u; return x.f;
}
__device__ __forceinline__ unsigned pkh(float a, float b) {
    union { _Float16 h[2]; unsigned u; } x;
    x.h[0] = (_Float16)a; x.h[1] = (_Float16)b; return x.u;
}
__device__ __forceinline__ float uph(unsigned w, int i) {
    union { unsigned u; _Float16 h[2]; } x; x.u = w;
    return (float)x.h[i];
}
// LDS-only barrier: lets wave-private global ops (NT stores, preloads) stay
// in flight across the barrier instead of the vmcnt(0) drain __syncthreads emits.
__device__ __forceinline__ void bar_lds() {
    asm volatile("s_waitcnt lgkmcnt(0)" ::: "memory");
    __builtin_amdgcn_s_barrier();
}

// ---------------- kernel 1: prep (weight transpose + X bf16 precast) ---------
__global__ __launch_bounds__(256) void prep_kernel(
    const float* __restrict__ wqs, const float* __restrict__ wks,
    const float* __restrict__ wvs, const float* __restrict__ wfc,
    const float* __restrict__ q, const float* __restrict__ k,
    const float* __restrict__ v, short* __restrict__ WT,
    short* __restrict__ Qb, short* __restrict__ Kb, short* __restrict__ Vb) {
    __shared__ float tile[32][33];
    int bx = blockIdx.x;
    int t = threadIdx.x;
    if (bx < 1024) {
        int mat = bx >> 8, tt = bx & 255;
        int k0 = (tt >> 4) * 32, n0 = (tt & 15) * 32;
        int tx = t & 31, ty = t >> 5;   // 32 x 8
        const float* src = (mat == 0) ? wqs : (mat == 1) ? wks : (mat == 2) ? wvs : wfc;
        short* dst = WT + (size_t)mat * DM * DM;
#pragma unroll
        for (int i = 0; i < 4; i++)
            tile[ty + i * 8][tx] = src[(size_t)(k0 + ty + i * 8) * DM + n0 + tx];
        __syncthreads();
#pragma unroll
        for (int i = 0; i < 4; i++)
            dst[(size_t)(n0 + ty + i * 8) * DM + k0 + tx] = f2bf(tile[tx][ty + i * 8]);
    } else {
        int cb2 = bx - 1024;
        const float* src; short* dst; size_t base; float sc = 1.0f;
        if (cb2 < 1024)      { src = q; dst = Qb; base = (size_t)cb2 * 2048; sc = QSCALE; }
        else if (cb2 < 3072) { src = k; dst = Kb; base = (size_t)(cb2 - 1024) * 2048; }
        else                 { src = v; dst = Vb; base = (size_t)(cb2 - 3072) * 2048; }
        size_t idx = base + (size_t)t * 8;
        float4 x0 = *(const float4*)(src + idx);
        float4 x1 = *(const float4*)(src + idx + 4);
        union { short s[8]; uint4 u; } pk;
        pk.s[0] = f2bf(x0.x * sc); pk.s[1] = f2bf(x0.y * sc);
        pk.s[2] = f2bf(x0.z * sc); pk.s[3] = f2bf(x0.w * sc);
        pk.s[4] = f2bf(x1.x * sc); pk.s[5] = f2bf(x1.y * sc);
        pk.s[6] = f2bf(x1.z * sc); pk.s[7] = f2bf(x1.w * sc);
        *(uint4*)(dst + idx) = pk.u;
    }
}

// ---------------- kernel 2: projections + prior transpose + mask compress ---
__global__ __launch_bounds__(256) void proj_all(
    const short* __restrict__ Xq, const short* __restrict__ Xk,
    const short* __restrict__ Xv, const short* __restrict__ WT,
    const float* __restrict__ prior, const float* __restrict__ km,
    const float* __restrict__ mm,
    short* __restrict__ QHb, short* __restrict__ KHb, short* __restrict__ VT,
    short* __restrict__ prtb, unsigned short* __restrict__ kmbits,
    unsigned short* __restrict__ mmbits) {
    __shared__ float tile[64][65];
    int bx = blockIdx.x;
    int t = threadIdx.x;
    if (bx >= 1344) {
        if (blockIdx.y != 0) return;
        int rr = (bx - 1344) * 4 + (t >> 6);    // row in [0, B*LQ)
        int lane = t & 63;
        const float* kmr = km + (size_t)rr * LK;
        const float* mmr = mm + (size_t)rr * LK;
        unsigned kb = 0, mb = 0;
#pragma unroll
        for (int c = 0; c < 4; c++) {
            float4 k4 = *(const float4*)(kmr + c * 256 + lane * 4);
            float4 m4 = *(const float4*)(mmr + c * 256 + lane * 4);
            kb |= (unsigned)(k4.x != 0.f) << (c * 4 + 0);
            kb |= (unsigned)(k4.y != 0.f) << (c * 4 + 1);
            kb |= (unsigned)(k4.z != 0.f) << (c * 4 + 2);
            kb |= (unsigned)(k4.w != 0.f) << (c * 4 + 3);
            mb |= (unsigned)(m4.x != 0.f) << (c * 4 + 0);
            mb |= (unsigned)(m4.y != 0.f) << (c * 4 + 1);
            mb |= (unsigned)(m4.z != 0.f) << (c * 4 + 2);
            mb |= (unsigned)(m4.w != 0.f) << (c * 4 + 3);
        }
        kmbits[(size_t)rr * 64 + lane] = (unsigned short)kb;
        mmbits[(size_t)rr * 64 + lane] = (unsigned short)mb;
        return;
    }
    if (bx >= 320) {
        if (blockIdx.y != 0) return;
        int tt = bx - 320;
        int b = tt >> 7, rem = tt & 127;        // 128 tiles: 16 (k) x 8 (q)
        int k0 = (rem >> 3) * 64, q0 = (rem & 7) * 64;
        int tx = t & 63, ty = t >> 6;           // 64 x 4
        const float* src = prior + (size_t)b * LK * LQ;
        short* dst = prtb + (size_t)b * LQ * LK;
#pragma unroll
        for (int i = 0; i < 16; i++)
            tile[ty + i * 4][tx] = src[(size_t)(k0 + ty + i * 4) * LQ + q0 + tx];
        __syncthreads();
#pragma unroll
        for (int i = 0; i < 16; i++)
            dst[(size_t)(q0 + ty + i * 4) * LK + k0 + tx] = f2bf(tile[tx][ty + i * 4] + 1e-8f);
        return;
    }
    const short* X; const short* W; short* out; int mode, r0;
    if (bx < 64)       { X = Xq; W = WT;          out = QHb; mode = 0; r0 = bx * 64; }
    else if (bx < 192) { X = Xk; W = WT + 262144; out = KHb; mode = 0; r0 = (bx - 64) * 64; }
    else               { X = Xv; W = WT + 524288; out = VT;  mode = 1; r0 = (bx - 192) * 64; }
    int tid = threadIdx.x;
    int wid = tid >> 6, lane = tid & 63, g = lane >> 4, ln = lane & 15;
    int wr = wid >> 1, wc = wid & 1;
    int cb = blockIdx.y * 256;
    f32x4 acc[4][2][2] = {};
    for (int kb = 0; kb < 16; kb++) {
        bf16x8 a[2];
#pragma unroll
        for (int i = 0; i < 2; i++) {
            int row = r0 + wr * 32 + i * 16 + ln;
            a[i] = *(const bf16x8*)(X + (size_t)row * DM + kb * 32 + g * 8);
        }
#pragma unroll
        for (int cc = 0; cc < 4; cc++) {
            bf16x8 b[2];
#pragma unroll
            for (int j = 0; j < 2; j++) {
                int col = cb + cc * 64 + wc * 32 + j * 16 + ln;
                b[j] = *(const bf16x8*)(W + (size_t)col * DM + kb * 32 + g * 8);
            }
#pragma unroll
            for (int i = 0; i < 2; i++)
#pragma unroll
                for (int j = 0; j < 2; j++)
                    acc[cc][i][j] = __builtin_amdgcn_mfma_f32_16x16x32_bf16(a[i], b[j], acc[cc][i][j], 0, 0, 0);
        }
    }
#pragma unroll
    for (int cc = 0; cc < 4; cc++)
#pragma unroll
        for (int i = 0; i < 2; i++)
#pragma unroll
            for (int j = 0; j < 2; j++) {
                int colg = cb + cc * 64 + wc * 32 + j * 16 + ln;
                if (mode == 0) {
#pragma unroll
                    for (int r = 0; r < 4; r++) {
                        int rowg = r0 + wr * 32 + i * 16 + g * 4 + r;
                        out[(size_t)rowg * DM + colg] = f2bf(acc[cc][i][j][r]);
                    }
                } else {
                    int hh = colg >> 6, d = colg & 63;
                    int rbase = r0 + wr * 32 + i * 16 + g * 4;
                    int bb = rbase >> 10, kk = rbase & 1023;
                    union { short s[4]; unsigned long long u; } pk;
#pragma unroll
                    for (int r = 0; r < 4; r++) pk.s[r] = f2bf(acc[cc][i][j][r]);
                    *(unsigned long long*)(out + ((size_t)((hh * B_ + bb) * DV + d)) * LK + kk) = pk.u;
                }
            }
}

// ---------------- kernel 3: fused attention (r16: NT stores, prW prefetch) --
#define SROWB 2064   // bytes per LDS row: 1032 halfs
__global__ __launch_bounds__(512, 6) void attn_kernel(
    const short* __restrict__ QHb, const short* __restrict__ KHb,
    const short* __restrict__ VT, const short* __restrict__ prtb,
    const unsigned short* __restrict__ kmbits, const unsigned short* __restrict__ mmbits,
    const float* __restrict__ qm, float* __restrict__ p_out,
    float* __restrict__ raw_out, float* __restrict__ lgp_out,
    short* __restrict__ outh) {
    __shared__ char lds[16 * SROWB];
    int tid = threadIdx.x;
    int wid = tid >> 6, lane = tid & 63, g = lane >> 4, ln = lane & 15;
    int q0 = blockIdx.x * 16, b = blockIdx.y, h = blockIdx.z;
    int kw0 = wid * 128;
    int row0 = wid * 2;
    const size_t rb0 = (size_t)(b * LQ + q0 + row0);

    // ---- preload bitmasks + qm + prior (latency hidden under pass A) ----
    unsigned kmb[2], mmb[2];
    float qmv[2];
    uint2 prW[2][4];
#pragma unroll
    for (int rr = 0; rr < 2; rr++) {
        kmb[rr] = kmbits[(rb0 + rr) * 64 + lane];
        mmb[rr] = mmbits[(rb0 + rr) * 64 + lane];
        qmv[rr] = qm[rb0 + rr];
#pragma unroll
        for (int c = 0; c < 4; c++)
            prW[rr][c] = *(const uint2*)(prtb + (rb0 + rr) * LK + c * 256 + lane * 4);
    }

    // ---- pass A: log2-domain scores into LDS (f16) ----
    {
        const short* qp = QHb + ((size_t)(b * LQ + q0 + ln)) * DM + h * DK + g * 8;
        bf16x8 bq0 = *(const bf16x8*)qp;
        bf16x8 bq1 = *(const bf16x8*)(qp + 32);
#pragma unroll
        for (int kt = 0; kt < 8; kt++) {
            int k0 = kw0 + kt * 16;
            const short* kp = KHb + ((size_t)(b * LK + k0 + ln)) * DM + h * DK + g * 8;
            bf16x8 ak0 = *(const bf16x8*)kp;
            bf16x8 ak1 = *(const bf16x8*)(kp + 32);
            f32x4 sa = {0.f, 0.f, 0.f, 0.f};
            sa = __builtin_amdgcn_mfma_f32_16x16x32_bf16(ak0, bq0, sa, 0, 0, 0);
            sa = __builtin_amdgcn_mfma_f32_16x16x32_bf16(ak1, bq1, sa, 0, 0, 0);
            uint2 sp;
            sp.x = pkh(sa[0], sa[1]);
            sp.y = pkh(sa[2], sa[3]);
            *(uint2*)(lds + ln * SROWB + (k0 + g * 4) * 2) = sp;
        }
    }
    bar_lds();

    // ---- pass B: per-wave rows; exp2 (single transcendental); bf16 carry ----
    float s1[2] = {0.f, 0.f}, s2[2] = {0.f, 0.f};
    uint2 xc[2][4];
#pragma unroll
    for (int rr = 0; rr < 2; rr++) {
        const char* svp = lds + (row0 + rr) * SROWB;
#pragma unroll
        for (int c = 0; c < 4; c++) {
            int e0 = c * 256 + lane * 4;
            uint2 prv = prW[rr][c];
            uint2 sp = *(const uint2*)(svp + e0 * 2);
            float sv[4] = { uph(sp.x, 0), uph(sp.x, 1), uph(sp.y, 0), uph(sp.y, 1) };
            float pr[4] = { bflo(prv.x), bfhi(prv.x), bflo(prv.y), bfhi(prv.y) };
            float xr[4];
#pragma unroll
            for (int r = 0; r < 4; r++) {
                float kmf = (float)((kmb[rr] >> (c * 4 + r)) & 1u);
                float e = kmf * __builtin_amdgcn_exp2f(sv[r] - C16);
                float x = e * pr[r];
                s1[rr] += e;
                s2[rr] += x;
                xr[r] = x;
            }
            xc[rr][c].x = pack2(xr[0], xr[1]);
            xc[rr][c].y = pack2(xr[2], xr[3]);
        }
    }
#pragma unroll
    for (int m = 1; m < 64; m <<= 1) {
        s1[0] += __shfl_xor(s1[0], m, 64);
        s1[1] += __shfl_xor(s1[1], m, 64);
        s2[0] += __shfl_xor(s2[0], m, 64);
        s2[1] += __shfl_xor(s2[1], m, 64);
    }

    // ---- pass C: contiguous non-temporal stores + LDS p-tile ----
#pragma unroll
    for (int rr = 0; rr < 2; rr++) {
        float inv1 = 1.0f / s1[rr];
        float inv2 = 1.0f / s2[rr];
        const size_t ob = ((size_t)((h * B_ + b) * LQ + q0 + row0 + rr)) * LK;
        short* pfp = (short*)(lds + (row0 + rr) * SROWB);
#pragma unroll
        for (int c = 0; c < 4; c++) {
            int e0 = c * 256 + lane * 4;
            float xv[4] = { bflo(xc[rr][c].x), bfhi(xc[rr][c].x),
                            bflo(xc[rr][c].y), bfhi(xc[rr][c].y) };
            f32x4 pw, rw, lw;
            union { short s[4]; unsigned long long u; } pk;
#pragma unroll
            for (int r = 0; r < 4; r++) {
                float mmf = (float)((mmb[rr] >> (c * 4 + r)) & 1u);
                float xr = xv[r];
                float p0 = xr * inv2;
                float praw = p0 * qmv[rr];
                float pfin = praw * mmf;
                float lgp = fmaxf(__logf(xr * inv1), -1e30f);
                pw[r] = pfin;
                rw[r] = praw;
                lw[r] = lgp;
                pk.s[r] = f2bf(pfin);
            }
            __builtin_nontemporal_store(pw, (f32x4*)(p_out + ob + e0));
            __builtin_nontemporal_store(rw, (f32x4*)(raw_out + ob + e0));
            __builtin_nontemporal_store(lw, (f32x4*)(lgp_out + ob + e0));
            *(unsigned long long*)(pfp + e0) = pk.u;
        }
    }
    bar_lds();

    // ---- pass D: PV on waves 0-3 ----
    if (wid >= 4) return;
    f32x4 oacc = {0.f, 0.f, 0.f, 0.f};
    int d0 = wid * 16;
    const short* vrow = VT + ((size_t)((h * B_ + b) * DV + d0 + ln)) * LK;
    const short* prow = (const short*)(lds + ln * SROWB);
    for (int kc = 0; kc < 32; kc++) {
        bf16x8 ap = *(const bf16x8*)(prow + kc * 32 + g * 8);
        bf16x8 bv = *(const bf16x8*)(vrow + kc * 32 + g * 8);
        oacc = __builtin_amdgcn_mfma_f32_16x16x32_bf16(ap, bv, oacc, 0, 0, 0);
    }
#pragma unroll
    for (int r = 0; r < 4; r++) {
        int row = q0 + g * 4 + r;
        outh[((size_t)(b * LQ + row)) * DM + h * DV + d0 + ln] = f2bf(oacc[r]);
    }
}

// ---------------- kernel 4: out = outh @ w_fc + residual --------------------
__global__ __launch_bounds__(256) void final_kernel(
    const short* __restrict__ outh, const short* __restrict__ WTfc,
    const float* __restrict__ qres, float* __restrict__ out) {
    int tid = threadIdx.x;
    int wid = tid >> 6, lane = tid & 63, g = lane >> 4, ln = lane & 15;
    int wr = wid >> 1, wc = wid & 1;
    int r0 = blockIdx.x * 64, c0 = blockIdx.y * 64;
    f32x4 acc[2][2] = {};
    for (int kb = 0; kb < 16; kb++) {
        bf16x8 a[2], b[2];
#pragma unroll
        for (int i = 0; i < 2; i++)
            a[i] = *(const bf16x8*)(outh + ((size_t)(r0 + wr * 32 + i * 16 + ln)) * DM + kb * 32 + g * 8);
#pragma unroll
        for (int j = 0; j < 2; j++)
            b[j] = *(const bf16x8*)(WTfc + ((size_t)(c0 + wc * 32 + j * 16 + ln)) * DM + kb * 32 + g * 8);
#pragma unroll
        for (int i = 0; i < 2; i++)
#pragma unroll
            for (int j = 0; j < 2; j++)
                acc[i][j] = __builtin_amdgcn_mfma_f32_16x16x32_bf16(a[i], b[j], acc[i][j], 0, 0, 0);
    }
#pragma unroll
    for (int i = 0; i < 2; i++)
#pragma unroll
        for (int j = 0; j < 2; j++)
#pragma unroll
            for (int r = 0; r < 4; r++) {
                int row = r0 + wr * 32 + i * 16 + g * 4 + r;
                int col = c0 + wc * 32 + j * 16 + ln;
                float v = acc[i][j][r] + qres[(size_t)row * DM + col];
                __builtin_nontemporal_store(v, out + (size_t)row * DM + col);
            }
}

extern "C" void kernel_launch(void* const* d_in, const int* in_sizes, int n_in,
                              void* d_out, int out_size, void* d_ws, size_t ws_size,
                              hipStream_t stream) {
    (void)in_sizes; (void)n_in; (void)out_size; (void)ws_size;
    const float* q     = (const float*)d_in[0];
    const float* k     = (const float*)d_in[1];
    const float* v     = (const float*)d_in[2];
    const float* wqs   = (const float*)d_in[3];
    const float* wks   = (const float*)d_in[4];
    const float* wvs   = (const float*)d_in[5];
    const float* wfc   = (const float*)d_in[6];
    const float* km    = (const float*)d_in[7];
    const float* qm    = (const float*)d_in[8];
    const float* mm    = (const float*)d_in[9];
    const float* prior = (const float*)d_in[10];

    char* ws = (char*)d_ws;
    short* WT               = (short*)(ws);                     // 2 MiB
    short* QHb              = (short*)(ws + 2097152);           // 4 MiB
    short* KHb              = (short*)(ws + 6291456);           // 8 MiB
    short* VT               = (short*)(ws + 14680064);          // 8 MiB
    short* prtb             = (short*)(ws + 23068672);          // 8 MiB (bf16)
    short* outh             = (short*)(ws + 31457280);          // 4 MiB
    unsigned short* kmbits  = (unsigned short*)(ws + 35651584); // 512 KiB
    unsigned short* mmbits  = (unsigned short*)(ws + 36175872); // 512 KiB
    short* Qb               = (short*)(ws + 36700160);          // 4 MiB (bf16, prescaled)
    short* Kb               = (short*)(ws + 40894464);          // 8 MiB
    short* Vb               = (short*)(ws + 49283072);          // 8 MiB -> ends 55 MiB

    float* out     = (float*)d_out;
    float* p_out   = out + 2097152;
    float* raw_out = p_out + 33554432;
    float* lgp_out = raw_out + 33554432;

    prep_kernel<<<dim3(6144), dim3(256), 0, stream>>>(wqs, wks, wvs, wfc, q, k, v,
                                                      WT, Qb, Kb, Vb);
    proj_all<<<dim3(2368, 2), 256, 0, stream>>>(Qb, Kb, Vb, WT, prior, km, mm,
                                                QHb, KHb, VT, prtb, kmbits, mmbits);
    attn_kernel<<<dim3(32, 8, 8), dim3(512), 0, stream>>>(QHb, KHb, VT, prtb, kmbits, mmbits,
                                                          qm, p_out, raw_out, lgp_out, outh);
    final_kernel<<<dim3(64, 8), 256, 0, stream>>>(outh, WT + 786432, q, out);
}